// Round 3
// baseline (683.013 us; speedup 1.0000x reference)
//
#include <hip/hip_runtime.h>
#include <stdint.h>

#define GW 8192
#define GMASK 8191
#define PLANE 67108864ULL   // elements per links plane
#define TPD 128             // tiles per dim (8192/64)
#define TMASK 127
#define NTILES 16384
#define QCAP 8192
#define WPR 128             // bitmap words per lattice row

typedef unsigned long long u64;
typedef unsigned int u32;

// ---------------- clear the 8 MB selection bitmap in ws ----------------------
__global__ void clear_bitmap_kernel(uint4* __restrict__ p, int n) {
    int i = blockIdx.x * blockDim.x + threadIdx.x;
    if (i < n) p[i] = make_uint4(0, 0, 0, 0);
}

// ---------------- detect on-device encoding of the bool 'links' --------------
// mode 0: 1-byte bool; mode 1: int32 0/1; mode 2: float32 0.0/1.0
// bool: ~45% nonzero at every byte%4. int32(1): only byte%4==0. float(1.0f):
// bytes %4==2 (0x80) and %4==3 (0x3f). So byte%4==1 nonzero <=> raw bool.
__global__ void detect_fmt_kernel(const unsigned char* __restrict__ links, int* __restrict__ flag) {
    __shared__ int c1, c3;
    if (threadIdx.x == 0) { c1 = 0; c3 = 0; }
    __syncthreads();
    int l1 = 0, l3 = 0;
    for (int i = threadIdx.x; i < 16384; i += blockDim.x) {
        if (links[i]) {
            int m = i & 3;
            if (m == 1) l1++;
            else if (m == 3) l3++;
        }
    }
    atomicAdd(&c1, l1);
    atomicAdd(&c3, l3);
    __syncthreads();
    if (threadIdx.x == 0) *flag = (c1 > 0) ? 0 : ((c3 > 0) ? 2 : 1);
}

// ---------------- bit-packing helpers ----------------------------------------
__device__ __forceinline__ u32 nib4(u32 w) {
    // bytes in {0,1} -> 4 bits, bit j = byte j
    return (((w & 0x01010101u) * 0x01020408u) >> 24) & 0xFu;
}
__device__ __forceinline__ u64 pack_row_b8(const unsigned char* p) {
    const uint4* q = (const uint4*)p;
    u64 w = 0;
#pragma unroll
    for (int i = 0; i < 4; i++) {
        uint4 v = q[i];
        u64 nb = (u64)(nib4(v.x) | (nib4(v.y) << 4) | (nib4(v.z) << 8) | (nib4(v.w) << 12));
        w |= nb << (16 * i);
    }
    return w;
}
__device__ __forceinline__ u64 pack_row_b32(const u32* p) {
    u64 w = 0;
#pragma unroll
    for (int k = 0; k < 16; k++) {
        uint4 v = ((const uint4*)p)[k];
        u64 nb = (u64)((v.x != 0) | ((v.y != 0) << 1) | ((v.z != 0) << 2) | ((v.w != 0) << 3));
        w |= nb << (4 * k);
    }
    return w;
}

// ---------------- single-block tile-granular BFS ------------------------------
// One wave processes one 64x64 tile: lane r holds row r as a 64-bit word.
// Global bitmap is monotone (atomicOr only). Level-synchronous over TILES.
__global__ void __launch_bounds__(1024)
bfs_tiles_kernel(const unsigned char* __restrict__ links8,
                 const int* __restrict__ seed_idx,
                 u64* __restrict__ bitmap,
                 const int* __restrict__ flag) {
    __shared__ unsigned short q[2][QCAP];
    __shared__ u32 tflags[NTILES / 32];
    __shared__ int s_cnt, s_ncnt, s_head, s_flip, s_mode;

    const int tid = threadIdx.x;
    const int ln  = tid & 63;

    for (int i = tid; i < NTILES / 32; i += 1024) tflags[i] = 0;
    if (tid == 0) {
        s_mode = *flag;
        int sr = seed_idx[0] & GMASK, sc = seed_idx[1] & GMASK;
        atomicOr(&bitmap[(u64)sr * WPR + (sc >> 6)], 1ull << (sc & 63));
        int t = (sr >> 6) * TPD + (sc >> 6);
        tflags[t >> 5] = 1u << (t & 31);
        q[0][0] = (unsigned short)t;
        s_cnt = 1; s_ncnt = 0; s_head = 0; s_flip = 0;
    }
    __syncthreads();

    const int mode = s_mode;
    const unsigned char* p0b = links8;
    const unsigned char* p1b = links8 + PLANE;
    const u32* p0w = (const u32*)links8;
    const u32* p1w = (const u32*)(links8 + PLANE * 4);

    int safety = 0;
    while (true) {
        const int flip = s_flip;
        const int cnt  = s_cnt;

        auto enq = [&](int t) {
            u32 bit = 1u << (t & 31);
            u32 old = atomicOr(&tflags[t >> 5], bit);
            if (!(old & bit)) {
                int p = atomicAdd(&s_ncnt, 1);
                if (p < QCAP) q[flip ^ 1][p] = (unsigned short)t;
            }
        };

        // drain current tile frontier (waves grab tiles independently)
        while (true) {
            int pos = 0;
            if (ln == 0) pos = atomicAdd(&s_head, 1);
            pos = __shfl(pos, 0);
            if (pos >= cnt) break;
            int t = q[flip][pos];
            int tR = t >> 7, tC = t & TMASK;
            if (ln == 0) atomicAnd(&tflags[t >> 5], ~(1u << (t & 31)));
            __threadfence_block();   // clear-before-read: late pushes re-enqueue us

            const int gr = tR * 64 + ln;        // this lane's global row
            u64* wp = &bitmap[(u64)gr * WPR + tC];
            u64 loaded = *(volatile u64*)wp;

            u64 l0, l1;                          // packed bonds for this row
            if (mode == 0) {
                l0 = pack_row_b8(p0b + (u64)gr * GW + tC * 64);
                l1 = pack_row_b8(p1b + (u64)gr * GW + tC * 64);
            } else {
                l0 = pack_row_b32(p0w + (u64)gr * GW + tC * 64);
                l1 = pack_row_b32(p1w + (u64)gr * GW + tC * 64);
            }

            // in-register fixpoint (wave-synchronous, no barriers)
            u64 sel = loaded;
            while (true) {
                u64 old = sel;
                sel |= (sel & l1) << 1;          // bond c: c -> c+1
                sel |= (sel >> 1) & l1;          // bond c: c+1 -> c
                u64 sb = sel & l0;               // bond r: r <-> r+1
                u64 up = __shfl_up(sb, 1);
                if (ln > 0) sel |= up;           // from row above
                u64 dn = __shfl_down(sel, 1);
                if (ln < 63) sel |= dn & l0;     // from row below
                if (__ballot(sel != old) == 0ull) break;
            }

            // write back own new bits (atomicOr: never erase concurrent pushes)
            u64 newbits = sel & ~loaded;
            if (newbits) atomicOr(wp, newbits);

            // ---- boundary pushes (torus-wrapped), enqueue on genuinely-new ----
            const int c0 = tC * 64;
            bool rnew = false, lnew = false;
            if ((sel >> 63) & (l1 >> 63) & 1ull) {   // bond c0+63: push right
                u64 old = atomicOr(&bitmap[(u64)gr * WPR + ((tC + 1) & TMASK)], 1ull);
                rnew = !(old & 1ull);
            }
            {   // bond (gr, c0-1): push left
                u64 lcol = (u64)((c0 - 1) & GMASK);
                bool lopen = (mode == 0) ? (p1b[(u64)gr * GW + lcol] != 0)
                                         : (p1w[(u64)gr * GW + lcol] != 0);
                if ((sel & 1ull) && lopen) {
                    u64 old = atomicOr(&bitmap[(u64)gr * WPR + ((tC - 1) & TMASK)], 1ull << 63);
                    lnew = !(old & (1ull << 63));
                }
            }
            u64 rmask = __ballot(rnew), lmask = __ballot(lnew);

            const int ga = (tR * 64 - 1) & GMASK;     // row above tile
            bool bopen = (mode == 0) ? (p0b[(u64)ga * GW + c0 + ln] != 0)
                                     : (p0w[(u64)ga * GW + c0 + ln] != 0);
            u64 top_sel = __shfl(sel, 0);
            u64 umask = __ballot(bopen && ((top_sel >> ln) & 1));
            u64 unew = 0;
            if (ln == 0 && umask) {
                u64 old = atomicOr(&bitmap[(u64)ga * WPR + tC], umask);
                unew = umask & ~old;
            }
            u64 dmask = sel & l0;                      // valid on lane 63
            const int gb = (tR * 64 + 64) & GMASK;     // row below tile
            u64 dnew = 0;
            if (ln == 63 && dmask) {
                u64 old = atomicOr(&bitmap[(u64)gb * WPR + tC], dmask);
                dnew = dmask & ~old;
            }

            if (ln == 0  && rmask) enq(tR * TPD + ((tC + 1) & TMASK));
            if (ln == 1  && lmask) enq(tR * TPD + ((tC - 1) & TMASK));
            if (ln == 0  && unew)  enq(((tR - 1) & TMASK) * TPD + tC);
            if (ln == 63 && dnew)  enq(((tR + 1) & TMASK) * TPD + tC);
        }

        __syncthreads();
        if (tid == 0) { s_cnt = s_ncnt; s_ncnt = 0; s_head = 0; s_flip ^= 1; }
        __syncthreads();
        if (s_cnt == 0) break;
        if (++safety > 30000) break;   // bug failsafe: terminate, never hang
    }
}

// ---------------- expand bitmap -> int32 output (write-bound, 256 MB) --------
__global__ void writeout_kernel(const u64* __restrict__ bitmap, int4* __restrict__ out) {
    int g = blockIdx.x * blockDim.x + threadIdx.x;  // int4 index
    int site0 = g << 2;
    u64 w = bitmap[site0 >> 6];
    u32 b = (u32)(w >> (site0 & 63)) & 0xFu;
    out[g] = make_int4(b & 1, (b >> 1) & 1, (b >> 2) & 1, (b >> 3) & 1);
}

extern "C" void kernel_launch(void* const* d_in, const int* in_sizes, int n_in,
                              void* d_out, int out_size, void* d_ws, size_t ws_size,
                              hipStream_t stream) {
    const unsigned char* links = (const unsigned char*)d_in[0];
    const int* seed = (const int*)d_in[1];

    int* flag   = (int*)d_ws;
    u64* bitmap = (u64*)((char*)d_ws + 4096);   // 8 MB

    // 1) clear bitmap (8 MB = 524288 uint4)
    clear_bitmap_kernel<<<2048, 256, 0, stream>>>((uint4*)bitmap, 524288);
    // 2) detect links encoding
    detect_fmt_kernel<<<1, 256, 0, stream>>>(links, flag);
    // 3) tile-granular flood fill
    bfs_tiles_kernel<<<1, 1024, 0, stream>>>(links, seed, bitmap, flag);
    // 4) expand to int32 output (subsumes zero-fill)
    writeout_kernel<<<65536, 256, 0, stream>>>(bitmap, (int4*)d_out);
}

// Round 4
// 661.613 us; speedup vs baseline: 1.0323x; 1.0323x over previous
//
#include <hip/hip_runtime.h>
#include <stdint.h>

#define GW 8192
#define GMASK 8191
#define PLANE 67108864ULL   // elements per links plane
#define TPD 128             // tiles per dim (8192/64)
#define TMASK 127
#define NTILES 16384
#define QCAP 16384          // ring entries (shorts, 32 KB)
#define QMASK 16383
#define WPR 128             // bitmap words per lattice row

typedef unsigned long long u64;
typedef unsigned int u32;

// ---------------- clear the 8 MB selection bitmap in ws ----------------------
__global__ void clear_bitmap_kernel(uint4* __restrict__ p, int n) {
    int i = blockIdx.x * blockDim.x + threadIdx.x;
    if (i < n) p[i] = make_uint4(0, 0, 0, 0);
}

// ---------------- bit-packing helpers ----------------------------------------
__device__ __forceinline__ u32 nib4(u32 w) {
    return (((w & 0x01010101u) * 0x01020408u) >> 24) & 0xFu;
}
__device__ __forceinline__ u64 pack_row_b8(const unsigned char* p) {
    const uint4* q = (const uint4*)p;
    u64 w = 0;
#pragma unroll
    for (int i = 0; i < 4; i++) {
        uint4 v = q[i];
        u64 nb = (u64)(nib4(v.x) | (nib4(v.y) << 4) | (nib4(v.z) << 8) | (nib4(v.w) << 12));
        w |= nb << (16 * i);
    }
    return w;
}
__device__ __forceinline__ u64 pack_row_b32(const u32* p) {
    u64 w = 0;
#pragma unroll
    for (int k = 0; k < 16; k++) {
        uint4 v = ((const uint4*)p)[k];
        u64 nb = (u64)((v.x != 0) | ((v.y != 0) << 1) | ((v.z != 0) << 2) | ((v.w != 0) << 3));
        w |= nb << (4 * k);
    }
    return w;
}

// ---------------- single-block ASYNC tile-granular BFS ------------------------
// One wave processes one 64x64 tile; tiles flow through a shared ring queue
// (no per-level barriers). Global bitmap is monotone (atomicOr only).
// Re-enqueue protocol: clear tflag BEFORE reading bitmap; pushers set tflag
// after their bitmap atomicOr completes (forced by using the returned old).
__global__ void __launch_bounds__(1024)
bfs_tiles_kernel(const unsigned char* __restrict__ links8,
                 const int* __restrict__ seed_idx,
                 u64* __restrict__ bitmap) {
    volatile __shared__ unsigned short q[QCAP];
    __shared__ u32 tflags[NTILES / 32];
    __shared__ int s_qhead, s_qtail, s_active, s_mode, s_c1, s_c3;

    const int tid = threadIdx.x;
    const int ln  = tid & 63;

    for (int i = tid; i < QCAP; i += 1024) q[i] = 0xFFFF;
    for (int i = tid; i < NTILES / 32; i += 1024) tflags[i] = 0;
    if (tid == 0) { s_c1 = 0; s_c3 = 0; s_qhead = 0; s_qtail = 0; s_active = 0; }
    __syncthreads();

    // ---- detect links encoding (mode 0: byte-bool, 1: int32, 2: float32) ----
    // byte%4==1 nonzero only for raw bool; byte%4==3 nonzero for bool/float.
    int l1c = 0, l3c = 0;
    for (int i = tid; i < 16384; i += 1024) {
        if (links8[i]) { int m = i & 3; if (m == 1) l1c++; else if (m == 3) l3c++; }
    }
    atomicAdd(&s_c1, l1c);
    atomicAdd(&s_c3, l3c);
    __syncthreads();
    if (tid == 0) {
        s_mode = (s_c1 > 0) ? 0 : ((s_c3 > 0) ? 2 : 1);
        int sr = seed_idx[0] & GMASK, sc = seed_idx[1] & GMASK;
        atomicOr(&bitmap[(u64)sr * WPR + (sc >> 6)], 1ull << (sc & 63));
        int t = (sr >> 6) * TPD + (sc >> 6);
        tflags[t >> 5] = 1u << (t & 31);
        q[0] = (unsigned short)t;
        s_qtail = 1; s_active = 1;
    }
    __syncthreads();

    const int mode = s_mode;
    const unsigned char* p0b = links8;
    const unsigned char* p1b = links8 + PLANE;
    const u32* p0w = (const u32*)links8;
    const u32* p1w = (const u32*)(links8 + PLANE * 4);

    auto enq = [&](int t2) {
        u32 bit = 1u << (t2 & 31);
        u32 old = atomicOr(&tflags[t2 >> 5], bit);
        if (!(old & bit)) {
            atomicAdd(&s_active, 1);               // before ticket: no false-zero
            int pos = atomicAdd(&s_qtail, 1) & QMASK;
            q[pos] = (unsigned short)t2;           // publish (sentinel scheme)
        }
    };

    long long guard = 0;
    while (true) {
        int t = -1;
        if (ln == 0) {
            while (true) {
                if (atomicAdd(&s_active, 0) == 0) break;          // all done
                int h  = atomicAdd(&s_qhead, 0);
                int tl = atomicAdd(&s_qtail, 0);
                if (h != tl && atomicCAS(&s_qhead, h, h + 1) == h) {
                    int pos = h & QMASK;
                    unsigned short v;
                    long long g2 = 0;
                    while ((v = q[pos]) == 0xFFFF) { if (++g2 > 400000000LL) break; }
                    q[pos] = 0xFFFF;                              // release slot
                    t = v;
                    break;
                }
                if (++guard > 400000000LL) break;                 // failsafe
            }
        }
        t = __shfl(t, 0);
        if (t < 0) break;

        const int tR = t >> 7, tC = t & TMASK;
        if (ln == 0) atomicAnd(&tflags[t >> 5], ~(1u << (t & 31)));
        __threadfence_block();   // clear-before-read: late pushes re-enqueue us

        const int gr = tR * 64 + ln;         // this lane's global row
        u64* wp = &bitmap[(u64)gr * WPR + tC];
        u64 loaded = *(volatile u64*)wp;

        u64 l0, l1;                          // packed bonds for this row
        if (mode == 0) {
            l0 = pack_row_b8(p0b + (u64)gr * GW + tC * 64);
            l1 = pack_row_b8(p1b + (u64)gr * GW + tC * 64);
        } else {
            l0 = pack_row_b32(p0w + (u64)gr * GW + tC * 64);
            l1 = pack_row_b32(p1w + (u64)gr * GW + tC * 64);
        }

        // ---- in-tile fixpoint: Kogge-Stone run-fill, both axes ----
        // P[i]: can jump c -> c+2^i horizontally (in-tile bonds only)
        u64 P0 = l1 & 0x7FFFFFFFFFFFFFFFull;          // drop boundary bond 63
        u64 P1 = P0 & (P0 >> 1);
        u64 P2 = P1 & (P1 >> 2);
        u64 P3 = P2 & (P2 >> 4);
        u64 P4 = P3 & (P3 >> 8);
        u64 P5 = P4 & (P4 >> 16);
        // D[i]: lane r can jump r -> r+2^i vertically (in-tile bonds only)
        u64 D0 = (ln < 63) ? l0 : 0ull;
        u64 D1 = D0 & __shfl_down(D0, 1);
        u64 D2 = D1 & __shfl_down(D1, 2);
        u64 D3 = D2 & __shfl_down(D2, 4);
        u64 D4 = D3 & __shfl_down(D3, 8);
        u64 D5 = D4 & __shfl_down(D4, 16);

        u64 sel = loaded;
        while (true) {
            u64 old = sel;
            // horizontal full run-fill (6 doubling rounds, both directions)
            sel |= (sel & P0) << 1;  sel |= (sel >> 1)  & P0;
            sel |= (sel & P1) << 2;  sel |= (sel >> 2)  & P1;
            sel |= (sel & P2) << 4;  sel |= (sel >> 4)  & P2;
            sel |= (sel & P3) << 8;  sel |= (sel >> 8)  & P3;
            sel |= (sel & P4) << 16; sel |= (sel >> 16) & P4;
            sel |= (sel & P5) << 32; sel |= (sel >> 32) & P5;
            // vertical full run-fill (shfl out-of-range returns own value:
            // up-dir ORs a subset of own sel = harmless; down-dir masked by D=0)
            sel |= __shfl_up(sel & D0, 1);  sel |= __shfl_down(sel, 1)  & D0;
            sel |= __shfl_up(sel & D1, 2);  sel |= __shfl_down(sel, 2)  & D1;
            sel |= __shfl_up(sel & D2, 4);  sel |= __shfl_down(sel, 4)  & D2;
            sel |= __shfl_up(sel & D3, 8);  sel |= __shfl_down(sel, 8)  & D3;
            sel |= __shfl_up(sel & D4, 16); sel |= __shfl_down(sel, 16) & D4;
            sel |= __shfl_up(sel & D5, 32); sel |= __shfl_down(sel, 32) & D5;
            if (__ballot(sel != old) == 0ull) break;
        }

        // write back own new bits (atomicOr: never erase concurrent pushes)
        u64 newbits = sel & ~loaded;
        if (newbits) atomicOr(wp, newbits);

        // ---- boundary pushes (torus-wrapped); enqueue only on genuinely-new.
        // Using the returned old forces vmcnt-completion before the LDS enq.
        const int c0 = tC * 64;
        bool rnew = false, lnew = false;
        if ((sel >> 63) & (l1 >> 63) & 1ull) {       // bond c0+63: push right
            u64 old = atomicOr(&bitmap[(u64)gr * WPR + ((tC + 1) & TMASK)], 1ull);
            rnew = !(old & 1ull);
        }
        {                                            // bond (gr, c0-1): push left
            u64 lcol = (u64)((c0 - 1) & GMASK);
            bool lopen = (mode == 0) ? (p1b[(u64)gr * GW + lcol] != 0)
                                     : (p1w[(u64)gr * GW + lcol] != 0);
            if ((sel & 1ull) && lopen) {
                u64 old = atomicOr(&bitmap[(u64)gr * WPR + ((tC - 1) & TMASK)], 1ull << 63);
                lnew = !(old & (1ull << 63));
            }
        }
        u64 rmask = __ballot(rnew), lmask = __ballot(lnew);

        const int ga = (tR * 64 - 1) & GMASK;        // row above tile
        bool bopen = (mode == 0) ? (p0b[(u64)ga * GW + c0 + ln] != 0)
                                 : (p0w[(u64)ga * GW + c0 + ln] != 0);
        u64 top_sel = __shfl(sel, 0);
        u64 umask = __ballot(bopen && ((top_sel >> ln) & 1));
        u64 unew = 0;
        if (ln == 0 && umask) {
            u64 old = atomicOr(&bitmap[(u64)ga * WPR + tC], umask);
            unew = umask & ~old;
        }
        u64 dmask = sel & l0;                        // valid on lane 63
        const int gb = (tR * 64 + 64) & GMASK;       // row below tile
        u64 dnew = 0;
        if (ln == 63 && dmask) {
            u64 old = atomicOr(&bitmap[(u64)gb * WPR + tC], dmask);
            dnew = dmask & ~old;
        }

        if (ln == 0  && rmask) enq(tR * TPD + ((tC + 1) & TMASK));
        if (ln == 1  && lmask) enq(tR * TPD + ((tC - 1) & TMASK));
        if (ln == 0  && unew)  enq(((tR - 1) & TMASK) * TPD + tC);
        if (ln == 63 && dnew)  enq(((tR + 1) & TMASK) * TPD + tC);

        // done with this tile (all lanes' enq atomics precede in program order)
        if (ln == 0) atomicSub(&s_active, 1);
    }
}

// ---------------- expand bitmap -> int32 output (write-bound, 256 MB) --------
__global__ void writeout_kernel(const u64* __restrict__ bitmap, int4* __restrict__ out) {
    int g = blockIdx.x * blockDim.x + threadIdx.x;  // int4 index
    int site0 = g << 2;
    u64 w = bitmap[site0 >> 6];
    u32 b = (u32)(w >> (site0 & 63)) & 0xFu;
    out[g] = make_int4(b & 1, (b >> 1) & 1, (b >> 2) & 1, (b >> 3) & 1);
}

extern "C" void kernel_launch(void* const* d_in, const int* in_sizes, int n_in,
                              void* d_out, int out_size, void* d_ws, size_t ws_size,
                              hipStream_t stream) {
    const unsigned char* links = (const unsigned char*)d_in[0];
    const int* seed = (const int*)d_in[1];

    u64* bitmap = (u64*)((char*)d_ws + 4096);   // 8 MB

    clear_bitmap_kernel<<<2048, 256, 0, stream>>>((uint4*)bitmap, 524288);
    bfs_tiles_kernel<<<1, 1024, 0, stream>>>(links, seed, bitmap);
    writeout_kernel<<<65536, 256, 0, stream>>>(bitmap, (int4*)d_out);
}